// Round 8
// baseline (538.830 us; speedup 1.0000x reference)
//
#include <hip/hip_runtime.h>
#include <hip/hip_bf16.h>

#define NROWS 16384
#define MCOLS 4096
#define DDIM  128
#define LOG2E 1.4426950408889634f

typedef __attribute__((ext_vector_type(8))) short short8;
typedef __attribute__((ext_vector_type(4))) float f32x4;

__device__ __forceinline__ float wave_reduce_add(float d) {
#pragma unroll
  for (int off = 32; off >= 1; off >>= 1) d += __shfl_xor(d, off, 64);
  return d;
}

__device__ __forceinline__ float pcalc(float t, int m) {
  float u = fmaxf(t, 0.2f * t);   // leaky_relu (commutes with positive log2e scaling)
  float e = exp2f(u);             // inputs pre-scaled by log2e
  return m != 0 ? e : 0.f;
}

// round-to-nearest-even f32 -> bf16 (valid for finite non-NaN inputs)
__device__ __forceinline__ unsigned short f2bf(float f) {
  unsigned u = __builtin_bit_cast(unsigned, f);
  return (unsigned short)((u + 0x7fffu + ((u >> 16) & 1u)) >> 16);
}

__device__ __forceinline__ unsigned pack_bf2(float lo, float hi) {
  return (unsigned)f2bf(lo) | ((unsigned)f2bf(hi) << 16);
}

// ---------------------------------------------------------------------------
// K1: s_neigh' = (V @ a_neigh)*log2e ; pack V -> bf16 in MFMA-B fragment order.
// chunkid = kt*16 + (ks2*8 + cf); entry = chunkid*64 + lane holds B[k][col]
// for k = kt*64 + ks2*32 + (lane>>4)*8 + b (b=0..7), col = cf*16 + (lane&15).
// ---------------------------------------------------------------------------
__global__ __launch_bounds__(256) void aggr_prep(
    const float* __restrict__ V, const float* __restrict__ a,
    float* __restrict__ sneigh, short* __restrict__ packedV) {
  const int t = threadIdx.x, lane = t & 63, w = t >> 6;
  const int blk = blockIdx.x;  // 0..255

  float a0 = a[DDIM + 2 * lane] * LOG2E;
  float a1 = a[DDIM + 2 * lane + 1] * LOG2E;
#pragma unroll
  for (int i = 0; i < 4; ++i) {
    int j = blk * 16 + w * 4 + i;
    float2 v = *(const float2*)(V + (long)j * DDIM + 2 * lane);
    float d = wave_reduce_add(v.x * a0 + v.y * a1);
    if (lane == 0) sneigh[j] = d;
  }

  const int tg = blk * 256 + t;       // == chunkid*64 + lane
  const int l = tg & 63;
  const int chunkid = tg >> 6;        // 0..1023
  const int c = chunkid & 15, kt = chunkid >> 4;
  const int ks2 = c >> 3, cf = c & 7;
  const int col = cf * 16 + (l & 15);
  const long krow = (long)kt * 64 + ks2 * 32 + (l >> 4) * 8;
  short8 o;
#pragma unroll
  for (int b = 0; b < 8; ++b) {
    float f = V[(krow + b) * DDIM + col];
    o[b] = (short)f2bf(f);
  }
  *(short8*)(packedV + (long)tg * 8) = o;
}

// ---------------------------------------------------------------------------
// K2: main — BARRIER-FREE main loop. 1024 blocks x 128 threads (2 waves:
// ks=0/1 K-halves of the same 16 rows) = 4 blocks/CU, 8 free-running waves.
// B-fragments live in a 2-slot VGPR ring loaded directly from L2-hot packedV
// (no LDS staging => no s_barrier => no vmcnt drain => mask loads from HBM
// stay in flight across iterations; compiler emits counted vmcnt waits).
// Mask: 4-slot register ring, ~3 iters of latency cover. One LDS sync pair
// only in the epilogue to combine the two K-halves.
// ---------------------------------------------------------------------------
#define LOADB(BUF_, I_)                                                        \
  {                                                                            \
    const short8* g_ =                                                         \
        (const short8*)packedV + (long)(ks * 32 + (I_)) * 1024 + lane;         \
    _Pragma("unroll") for (int c = 0; c < 16; ++c) Bfr[BUF_][c] = g_[c * 64];  \
  }

#define LOADM(S_, I_)                                                          \
  {                                                                            \
    _Pragma("unroll") for (int ks2 = 0; ks2 < 2; ++ks2)                        \
        _Pragma("unroll") for (int q = 0; q < 2; ++q)                          \
            rg[S_][ks2 * 2 + q] =                                              \
        *(const int4*)(mbase + (I_)*64 + ks2 * 32 + q * 4);                    \
  }

#define BODY(I, MS, MLS, BUF)                                                  \
  {                                                                            \
    const int i_ = (I);                                                        \
    if (i_ < 31) LOADB((BUF) ^ 1, i_ + 1);                                     \
    __builtin_amdgcn_sched_barrier(0);                                         \
    if (i_ < 29) LOADM(MLS, i_ + 3);                                           \
    __builtin_amdgcn_sched_barrier(0);                                         \
    short8 afr[2];                                                             \
    _Pragma("unroll") for (int ks2 = 0; ks2 < 2; ++ks2) {                      \
      const float* sj = &s_sn[(ks * 32 + i_) * 64 + ks2 * 32 + kg * 8];        \
      float4 s0 = *(const float4*)sj;                                          \
      float4 s1 = *(const float4*)(sj + 4);                                    \
      int4 m0 = rg[MS][ks2 * 2], m1 = rg[MS][ks2 * 2 + 1];                     \
      float p0 = pcalc(si + s0.x, m0.x);                                       \
      float p1 = pcalc(si + s0.y, m0.y);                                       \
      float p2 = pcalc(si + s0.z, m0.z);                                       \
      float p3 = pcalc(si + s0.w, m0.w);                                       \
      float p4 = pcalc(si + s1.x, m1.x);                                       \
      float p5 = pcalc(si + s1.y, m1.y);                                       \
      float p6 = pcalc(si + s1.z, m1.z);                                       \
      float p7 = pcalc(si + s1.w, m1.w);                                       \
      den += ((p0 + p1) + (p2 + p3)) + ((p4 + p5) + (p6 + p7));                \
      int4 ai;                                                                 \
      ai.x = (int)pack_bf2(p0, p1);                                            \
      ai.y = (int)pack_bf2(p2, p3);                                            \
      ai.z = (int)pack_bf2(p4, p5);                                            \
      ai.w = (int)pack_bf2(p6, p7);                                            \
      afr[ks2] = __builtin_bit_cast(short8, ai);                               \
    }                                                                          \
    _Pragma("unroll") for (int cf = 0; cf < 8; ++cf) {                         \
      acc[cf] = __builtin_amdgcn_mfma_f32_16x16x32_bf16(                       \
          afr[0], Bfr[BUF][cf], acc[cf], 0, 0, 0);                             \
      acc[cf] = __builtin_amdgcn_mfma_f32_16x16x32_bf16(                       \
          afr[1], Bfr[BUF][8 + cf], acc[cf], 0, 0, 0);                         \
    }                                                                          \
  }

__global__ __launch_bounds__(128, 2) void aggr_main(
    const float* __restrict__ self_feats, const int* __restrict__ nm,
    const float* __restrict__ a, const float* __restrict__ sneigh,
    const short* __restrict__ packedV, float* __restrict__ out) {
  __shared__ float s_sn[MCOLS];  // 16 KB: s_neigh'; epilogue comb overlays it

  const int t = threadIdx.x, lane = t & 63, ks = t >> 6;  // 2 waves: ks=0,1
  const int rowblk = blockIdx.x * 16;
  const int arow = lane & 15, kg = lane >> 4;
  const int row = rowblk + arow;

  short8 Bfr[2][16];  // 2-slot B ring (static indices only)
  int4 rg[4][4];      // 4-slot mask ring (static indices only)
  const int* mbase = nm + (long)row * MCOLS + ks * 2048 + kg * 8;

  // prologue loads (retired by the __syncthreads drain below — one-time cost)
  LOADB(0, 0)
  LOADM(0, 0)
  LOADM(1, 1)
  LOADM(2, 2)

  // s_self' for this lane's row: register dot + 2 shuffles (no LDS)
  float sip = 0.f;
  {
    const float* rp = self_feats + (long)row * DDIM + kg * 32;
    const float* ap = a + kg * 32;
#pragma unroll
    for (int j = 0; j < 8; ++j) {
      float4 v = *(const float4*)(rp + j * 4);
      float4 av = *(const float4*)(ap + j * 4);
      sip += v.x * av.x + v.y * av.y + v.z * av.z + v.w * av.w;
    }
  }
  sip += __shfl_xor(sip, 16, 64);
  sip += __shfl_xor(sip, 32, 64);
  const float si = sip * LOG2E;

  // s_neigh' -> LDS (coalesced, 8 float4 per thread)
  {
    const float4* src = (const float4*)sneigh;
    float4* dst = (float4*)s_sn;
#pragma unroll
    for (int j = 0; j < 8; ++j) dst[t + j * 128] = src[t + j * 128];
  }
  __syncthreads();  // s_sn ready (also drains prologue loads — one-time)

  f32x4 acc[8];
#pragma unroll
  for (int i = 0; i < 8; ++i) acc[i] = (f32x4){0.f, 0.f, 0.f, 0.f};
  float den = 0.f;

  for (int it = 0; it < 32; it += 4) {
    BODY(it + 0, 0, 3, 0)
    BODY(it + 1, 1, 0, 1)
    BODY(it + 2, 2, 1, 0)
    BODY(it + 3, 3, 2, 1)
  }

  // den over the 4 kg groups -> lane holds den(row=arow) for its ks half
  den += __shfl_xor(den, 16, 64);
  den += __shfl_xor(den, 32, 64);

  __syncthreads();  // both waves done with s_sn; safe to overlay comb
  float* comb = s_sn;            // [16][132] f32
  float* den_x = s_sn + 2200;    // 16 f32
  if (ks == 1) {
#pragma unroll
    for (int cf = 0; cf < 8; ++cf)
#pragma unroll
      for (int r = 0; r < 4; ++r)
        comb[(kg * 4 + r) * 132 + cf * 16 + arow] = acc[cf][r];
    if (lane < 16) den_x[lane] = den;
  }
  __syncthreads();
  if (ks == 0) {
    float dtot = den + den_x[arow];
    float rcp[4];
#pragma unroll
    for (int r = 0; r < 4; ++r) {
      float dv = __shfl(dtot, kg * 4 + r, 64);
      rcp[r] = dv > 0.f ? 1.0f / dv : 0.f;
    }
#pragma unroll
    for (int cf = 0; cf < 8; ++cf)
#pragma unroll
      for (int r = 0; r < 4; ++r)
        out[(long)(rowblk + kg * 4 + r) * DDIM + cf * 16 + arow] =
            (acc[cf][r] + comb[(kg * 4 + r) * 132 + cf * 16 + arow]) * rcp[r];
  }
}

extern "C" void kernel_launch(void* const* d_in, const int* in_sizes, int n_in,
                              void* d_out, int out_size, void* d_ws, size_t ws_size,
                              hipStream_t stream) {
  const float* self_feats = (const float*)d_in[0];
  const float* V = (const float*)d_in[1];           // features_neighs
  const int* nm = (const int*)d_in[2];              // neigh_matrix
  const float* a = (const float*)d_in[3];
  float* out = (float*)d_out;

  float* sneigh = (float*)d_ws;                     // 16 KB @ 0
  short* packedV = (short*)((char*)d_ws + 16384);   // 1 MB @ 16 KB

  aggr_prep<<<256, 256, 0, stream>>>(V, a, sneigh, packedV);
  aggr_main<<<1024, 128, 0, stream>>>(self_feats, nm, a, sneigh, packedV, out);
}

// Round 10
// 404.247 us; speedup vs baseline: 1.3329x; 1.3329x over previous
//
#include <hip/hip_runtime.h>
#include <hip/hip_bf16.h>

#define NROWS 16384
#define MCOLS 4096
#define DDIM  128
#define LOG2E 1.4426950408889634f
#define NSPLIT 8
#define SCOLS 512
#define ITERS 8   // SCOLS / 64

typedef __attribute__((ext_vector_type(8))) short short8;
typedef __attribute__((ext_vector_type(4))) float f32x4;

__device__ __forceinline__ float wave_reduce_add(float d) {
#pragma unroll
  for (int off = 32; off >= 1; off >>= 1) d += __shfl_xor(d, off, 64);
  return d;
}

__device__ __forceinline__ float pcalc(float t, int m) {
  float u = fmaxf(t, 0.2f * t);   // leaky_relu (commutes with positive log2e scale)
  float e = exp2f(u);             // inputs pre-scaled by log2e
  return m != 0 ? e : 0.f;
}

// round-to-nearest-even f32 -> bf16 (valid for finite non-NaN inputs)
__device__ __forceinline__ unsigned short f2bf(float f) {
  unsigned u = __builtin_bit_cast(unsigned, f);
  return (unsigned short)((u + 0x7fffu + ((u >> 16) & 1u)) >> 16);
}

__device__ __forceinline__ unsigned pack_bf2(float lo, float hi) {
  return (unsigned)f2bf(lo) | ((unsigned)f2bf(hi) << 16);
}

// ---------------------------------------------------------------------------
// K1: s_neigh' = (V @ a_neigh)*log2e ; pack V -> bf16 in MFMA-B fragment order.
// chunkid = kt*16 + (ks2*8 + cf); entry = chunkid*64 + lane holds B[k][col]
// for k = kt*64 + ks2*32 + (lane>>4)*8 + b (b=0..7), col = cf*16 + (lane&15).
// ---------------------------------------------------------------------------
__global__ __launch_bounds__(256) void aggr_prep(
    const float* __restrict__ V, const float* __restrict__ a,
    float* __restrict__ sneigh, short* __restrict__ packedV) {
  const int t = threadIdx.x, lane = t & 63, w = t >> 6;
  const int blk = blockIdx.x;  // 0..255

  float a0 = a[DDIM + 2 * lane] * LOG2E;
  float a1 = a[DDIM + 2 * lane + 1] * LOG2E;
#pragma unroll
  for (int i = 0; i < 4; ++i) {
    int j = blk * 16 + w * 4 + i;
    float2 v = *(const float2*)(V + (long)j * DDIM + 2 * lane);
    float d = wave_reduce_add(v.x * a0 + v.y * a1);
    if (lane == 0) sneigh[j] = d;
  }

  const int tg = blk * 256 + t;       // == chunkid*64 + lane
  const int l = tg & 63;
  const int chunkid = tg >> 6;        // 0..1023
  const int c = chunkid & 15, kt = chunkid >> 4;
  const int ks2 = c >> 3, cf = c & 7;
  const int col = cf * 16 + (l & 15);
  const long krow = (long)kt * 64 + ks2 * 32 + (l >> 4) * 8;
  short8 o;
#pragma unroll
  for (int b = 0; b < 8; ++b) {
    float f = V[(krow + b) * DDIM + col];
    o[b] = (short)f2bf(f);
  }
  *(short8*)(packedV + (long)tg * 8) = o;
}

// ---------------------------------------------------------------------------
// K2: split-main. Grid 1024 = 128 row-blocks x 8 K-splits; 512 thr (8 waves).
// The split's V-slice (128 KB) is loaded into LDS ONCE in the prologue and
// never restaged -> the K-loop's ONLY vmem ops are the mask loads. The mask
// register ring (3 iters deep) therefore gets genuine 3-iteration latency
// cover: in-order vmcnt retirement cannot chain a fast load behind old masks
// because there are no other loads. No barriers in the loop; 8 independent
// waves per CU. Each wave owns 16 rows x 512 cols and writes f32 partial
// num/den; K3 combines.
// ---------------------------------------------------------------------------
#define LOADM(S_, I_)                                                          \
  {                                                                            \
    _Pragma("unroll") for (int ks2 = 0; ks2 < 2; ++ks2)                        \
        _Pragma("unroll") for (int q = 0; q < 2; ++q)                          \
            rg[S_][ks2 * 2 + q] =                                              \
        *(const int4*)(mbase + (I_)*64 + ks2 * 32 + q * 4);                    \
  }

#define BODYS(I, VMC)                                                          \
  {                                                                            \
    const int i_ = (I);                                                        \
    if (i_ < ITERS - 3) LOADM((i_ + 3) & 3, i_ + 3);                           \
    __builtin_amdgcn_sched_barrier(0);                                         \
    asm volatile("s_waitcnt vmcnt(" #VMC ")" ::: "memory");                    \
    __builtin_amdgcn_sched_barrier(0);                                         \
    short8 afr[2];                                                             \
    _Pragma("unroll") for (int ks2 = 0; ks2 < 2; ++ks2) {                      \
      const float* sj = &s_sn[i_ * 64 + ks2 * 32 + kg * 8];                    \
      float4 s0 = *(const float4*)sj;                                          \
      float4 s1 = *(const float4*)(sj + 4);                                    \
      int4 m0 = rg[(I) & 3][ks2 * 2], m1 = rg[(I) & 3][ks2 * 2 + 1];           \
      float p0 = pcalc(si + s0.x, m0.x);                                       \
      float p1 = pcalc(si + s0.y, m0.y);                                       \
      float p2 = pcalc(si + s0.z, m0.z);                                       \
      float p3 = pcalc(si + s0.w, m0.w);                                       \
      float p4 = pcalc(si + s1.x, m1.x);                                       \
      float p5 = pcalc(si + s1.y, m1.y);                                       \
      float p6 = pcalc(si + s1.z, m1.z);                                       \
      float p7 = pcalc(si + s1.w, m1.w);                                       \
      den += ((p0 + p1) + (p2 + p3)) + ((p4 + p5) + (p6 + p7));                \
      int4 ai;                                                                 \
      ai.x = (int)pack_bf2(p0, p1);                                            \
      ai.y = (int)pack_bf2(p2, p3);                                            \
      ai.z = (int)pack_bf2(p4, p5);                                            \
      ai.w = (int)pack_bf2(p6, p7);                                            \
      afr[ks2] = __builtin_bit_cast(short8, ai);                               \
    }                                                                          \
    _Pragma("unroll") for (int cf = 0; cf < 8; ++cf) {                         \
      acc[cf] = __builtin_amdgcn_mfma_f32_16x16x32_bf16(                       \
          afr[0], Bl[(i_ * 16 + cf) * 64 + lane], acc[cf], 0, 0, 0);           \
      acc[cf] = __builtin_amdgcn_mfma_f32_16x16x32_bf16(                       \
          afr[1], Bl[(i_ * 16 + 8 + cf) * 64 + lane], acc[cf], 0, 0, 0);       \
    }                                                                          \
  }

__global__ __launch_bounds__(512, 2) void aggr_mainsp(
    const float* __restrict__ self_feats, const int* __restrict__ nm,
    const float* __restrict__ a, const float* __restrict__ sneigh,
    const short* __restrict__ packedV, float* __restrict__ num,
    float* __restrict__ den_out) {
  __shared__ __align__(16) short Bs[SCOLS * DDIM];  // 128 KB, loaded once
  __shared__ float s_sn[SCOLS];                     // 2 KB

  const int t = threadIdx.x, lane = t & 63, w = t >> 6;  // 8 waves
  const int split = blockIdx.x & 7;
  const int rowblk = (blockIdx.x >> 3) * 128;
  const int arow = lane & 15, kg = lane >> 4;
  const int row = rowblk + w * 16 + arow;

  // prologue: B-slice -> LDS (16 rounds x 8 KB, linear; drained by syncthreads)
  {
    const short* gb = packedV + (long)split * (SCOLS * DDIM);
#pragma unroll
    for (int r = 0; r < 16; ++r) {
      __builtin_amdgcn_global_load_lds(
          (const __attribute__((address_space(1))) void*)(gb + (r * 512 + t) * 8),
          (__attribute__((address_space(3))) void*)(&Bs[(r * 512 + t) * 8]),
          16, 0, 0);
    }
  }
  // s_neigh' slice -> LDS
  if (t < 128)
    ((float4*)s_sn)[t] = ((const float4*)(sneigh + split * SCOLS))[t];

  // s_self' for this lane's row: register dot + 2 shuffles
  float sip = 0.f;
  {
    const float* rp = self_feats + (long)row * DDIM + kg * 32;
    const float* ap = a + kg * 32;
#pragma unroll
    for (int j = 0; j < 8; ++j) {
      float4 v = *(const float4*)(rp + j * 4);
      float4 av = *(const float4*)(ap + j * 4);
      sip += v.x * av.x + v.y * av.y + v.z * av.z + v.w * av.w;
    }
  }
  sip += __shfl_xor(sip, 16, 64);
  sip += __shfl_xor(sip, 32, 64);
  const float si = sip * LOG2E;

  // mask ring: 3 iterations deep (registers survive the barrier)
  const int* mbase = nm + (long)row * MCOLS + split * SCOLS + kg * 8;
  int4 rg[4][4];
  LOADM(0, 0)
  LOADM(1, 1)
  LOADM(2, 2)

  __syncthreads();  // one-time: drains B-stage + prologue loads; LDS ready

  const short8* Bl = (const short8*)Bs;
  f32x4 acc[8];
#pragma unroll
  for (int i = 0; i < 8; ++i) acc[i] = (f32x4){0.f, 0.f, 0.f, 0.f};
  float den = 0.f;

  // 8 iterations, no barriers, masks are the ONLY vmem ops in flight
  BODYS(0, 12)
  BODYS(1, 12)
  BODYS(2, 12)
  BODYS(3, 12)
  BODYS(4, 12)
  BODYS(5, 8)
  BODYS(6, 4)
  BODYS(7, 0)

  // den over the 4 kg groups -> every lane holds den(row = arow)
  den += __shfl_xor(den, 16, 64);
  den += __shfl_xor(den, 32, 64);
  if (lane < 16)
    den_out[(long)split * NROWS + rowblk + w * 16 + lane] = den;

#pragma unroll
  for (int cf = 0; cf < 8; ++cf)
#pragma unroll
    for (int r = 0; r < 4; ++r)
      num[((long)split * NROWS + rowblk + w * 16 + kg * 4 + r) * DDIM +
          cf * 16 + arow] = acc[cf][r];
}

// ---------------------------------------------------------------------------
// K3: combine. out[row][d] = sum_s num[s][row][d] / sum_s den[s][row].
// 8192 blocks x 256 thr: block = 2 rows x 128 d. Streaming, coalesced.
// ---------------------------------------------------------------------------
__global__ __launch_bounds__(256) void aggr_comb(
    const float* __restrict__ num, const float* __restrict__ den,
    float* __restrict__ out) {
  __shared__ float sden[2][8];
  const int t = threadIdx.x;
  const long blk = blockIdx.x;
  const int r = t >> 7, d = t & 127;
  const long row = blk * 2 + r;

  if (t < 16) sden[t >> 3][t & 7] = den[(long)(t & 7) * NROWS + blk * 2 + (t >> 3)];
  __syncthreads();

  float s = 0.f;
#pragma unroll
  for (int q = 0; q < 8; ++q) s += sden[r][q];
  float rcp = s > 0.f ? 1.0f / s : 0.f;

  float accv = 0.f;
#pragma unroll
  for (int q = 0; q < 8; ++q) accv += num[((long)q * NROWS + row) * DDIM + d];
  out[row * DDIM + d] = accv * rcp;
}

extern "C" void kernel_launch(void* const* d_in, const int* in_sizes, int n_in,
                              void* d_out, int out_size, void* d_ws, size_t ws_size,
                              hipStream_t stream) {
  const float* self_feats = (const float*)d_in[0];
  const float* V = (const float*)d_in[1];           // features_neighs
  const int* nm = (const int*)d_in[2];              // neigh_matrix
  const float* a = (const float*)d_in[3];
  float* out = (float*)d_out;

  float* sneigh = (float*)d_ws;                               // 16 KB @ 0
  short* packedV = (short*)((char*)d_ws + (1 << 14));         // 1 MB @ 16 KB
  float* num = (float*)((char*)d_ws + (1l << 21));            // 64 MB @ 2 MB
  float* den = (float*)((char*)d_ws + (1l << 21) + (1l << 26));  // 512 KB @ 66 MB

  aggr_prep<<<256, 256, 0, stream>>>(V, a, sneigh, packedV);
  aggr_mainsp<<<1024, 512, 0, stream>>>(self_feats, nm, a, sneigh, packedV,
                                        num, den);
  aggr_comb<<<8192, 256, 0, stream>>>(num, den, out);
}